// Round 1
// baseline (49125.519 us; speedup 1.0000x reference)
//
#include <hip/hip_runtime.h>

#define B_TOT 128
#define T_LEN 800
#define I_DIM 9
#define H_DIM 1024
#define O_DIM 8
#define NB    16            // batches per block (one M=16 MFMA tile)
#define HPAD  (H_DIM + 8)   // +8 bf16 = 16B pad -> breaks 16-way LDS bank conflict

typedef float f32x4 __attribute__((ext_vector_type(4)));
typedef short s16x8 __attribute__((ext_vector_type(8)));

__device__ __forceinline__ unsigned short f2bf(float f) {
    unsigned u = __float_as_uint(f);
    u += 0x7fffu + ((u >> 16) & 1u);   // round-to-nearest-even
    return (unsigned short)(u >> 16);
}

// ---------------- prep: Wrec f32 -> bf16 (row-major [n][k]) ----------------
__global__ void cvt_wrec(const float* __restrict__ w, unsigned short* __restrict__ o) {
    const int i = (blockIdx.x * 256 + threadIdx.x) * 4;   // grid covers 1M elems
    float4 v = *(const float4*)(w + i);
    ushort4 r;
    r.x = f2bf(v.x); r.y = f2bf(v.y); r.z = f2bf(v.z); r.w = f2bf(v.w);
    *(ushort4*)(o + i) = r;
}

// ---------------- recurrent scan: 8 persistent blocks, 16 batches each ------
__global__ __launch_bounds__(1024)
void rnn_scan(const float* __restrict__ x,        // [B][T][9]
              const float* __restrict__ noise,    // [B][T][H]
              const float* __restrict__ Win,      // [H][9]
              const unsigned short* __restrict__ Wb, // Wrec bf16 [n][k]
              float* __restrict__ hiddens)        // [B][T][H] (f32 out)
{
    __shared__ unsigned short h_bf[NB][HPAD];   // 33 KB  (bf16 copy of h for MFMA A)
    __shared__ float drive[NB][H_DIM];          // 64 KB
    __shared__ float xs[NB][I_DIM];             // x broadcast

    const int tid  = threadIdx.x;
    const int lane = tid & 63;
    const int wave = tid >> 6;          // 16 waves
    const int b0   = blockIdx.x * NB;
    const int n0   = wave * 64;         // this wave's N-slice (4 tiles of 16)
    const int l15  = lane & 15;
    const int kb   = lane >> 4;         // k-block / D-row-group

    // Win row for h' = tid lives in registers
    float win[I_DIM];
#pragma unroll
    for (int i = 0; i < I_DIM; ++i) win[i] = Win[tid * I_DIM + i];

    // init hidden state to zero
#pragma unroll
    for (int b = 0; b < NB; ++b) h_bf[b][tid] = 0;

    // f32 master copy of h: each lane owns exactly its D-fragment elements
    float hreg[4][4];
#pragma unroll
    for (int nt = 0; nt < 4; ++nt)
#pragma unroll
        for (int r = 0; r < 4; ++r) hreg[nt][r] = 0.f;

    __syncthreads();

#pragma unroll 1
    for (int t = 0; t < T_LEN; ++t) {
        // (a1) stage x[b][t][:] for the block's 16 batches
        if (tid < NB * I_DIM) {
            int b = tid / I_DIM, i = tid - b * I_DIM;
            xs[b][i] = x[(size_t)(b0 + b) * (T_LEN * I_DIM) + t * I_DIM + i];
        }
        __syncthreads();   // B0: xs visible; prev-step h_bf writes visible

        // (a2) drive[b][tid] = 0.1*noise + x·Win^T   (tid == h')
#pragma unroll 4
        for (int b = 0; b < NB; ++b) {
            float d = 0.1f * noise[((size_t)(b0 + b) * T_LEN + t) * H_DIM + tid];
#pragma unroll
            for (int i = 0; i < I_DIM; ++i) d += win[i] * xs[b][i];
            drive[b][tid] = d;
        }
        __syncthreads();   // B1: drive visible

        // (b) GEMM: pre[b][n] = sum_k h[b][k] * Wrec[n][k]
        f32x4 acc[4];
#pragma unroll
        for (int nt = 0; nt < 4; ++nt) acc[nt] = (f32x4){0.f, 0.f, 0.f, 0.f};

#pragma unroll 2
        for (int k0 = 0; k0 < H_DIM; k0 += 32) {
            // A-frag: lane l -> A[row=l&15][k = (l>>4)*8 + e]
            s16x8 af = *(const s16x8*)&h_bf[l15][k0 + kb * 8];
#pragma unroll
            for (int nt = 0; nt < 4; ++nt) {
                const int n = n0 + nt * 16 + l15;
                // B-frag: lane l -> B[k=(l>>4)*8+e][col=l&15] = Wrec[n][k] contiguous
                s16x8 bf = *(const s16x8*)&Wb[(size_t)n * H_DIM + k0 + kb * 8];
                acc[nt] = __builtin_amdgcn_mfma_f32_16x16x32_bf16(af, bf, acc[nt], 0, 0, 0);
            }
        }

        // (c) epilogue: D[row=(l>>4)*4+r][col=l&15]; h_new = 0.9h + 0.1relu(pre)
#pragma unroll
        for (int nt = 0; nt < 4; ++nt) {
            const int n = n0 + nt * 16 + l15;
#pragma unroll
            for (int r = 0; r < 4; ++r) {
                const int b = kb * 4 + r;
                float pre = acc[nt][r] + drive[b][n];
                float hn  = 0.9f * hreg[nt][r] + 0.1f * fmaxf(pre, 0.f);
                hreg[nt][r] = hn;
                hiddens[((size_t)(b0 + b) * T_LEN + t) * H_DIM + n] = hn;
            }
        }
        __syncthreads();   // B2: all waves done reading h_bf + drive

        // (d) publish bf16 h for next step's A-frags
#pragma unroll
        for (int nt = 0; nt < 4; ++nt) {
            const int n = n0 + nt * 16 + l15;
#pragma unroll
            for (int r = 0; r < 4; ++r)
                h_bf[kb * 4 + r][n] = f2bf(hreg[nt][r]);
        }
    }
}

// ---------------- output head: logits + softmax ----------------------------
__global__ __launch_bounds__(256)
void out_head(const float* __restrict__ hiddens, const float* __restrict__ Wout,
              float* __restrict__ outs)
{
    __shared__ float wlds[O_DIM][H_DIM];   // 32 KB
    const int tid = threadIdx.x;
    for (int j = tid; j < (O_DIM * H_DIM) / 4; j += 256)
        ((float4*)wlds)[j] = ((const float4*)Wout)[j];
    __syncthreads();

    const int wave = tid >> 6, lane = tid & 63;
#pragma unroll
    for (int rr = 0; rr < 2; ++rr) {
        const size_t row = (size_t)blockIdx.x * 8 + wave * 2 + rr;  // < 102400
        const float* hp = hiddens + row * H_DIM;

        float a0=0,a1=0,a2=0,a3=0,a4=0,a5=0,a6=0,a7=0;
#pragma unroll
        for (int j = 0; j < 4; ++j) {
            float4 hv = *(const float4*)(hp + lane * 4 + j * 256);
#define DOT(o, acc) { float4 wv = *(const float4*)&wlds[o][lane*4 + j*256]; \
                      acc += hv.x*wv.x + hv.y*wv.y + hv.z*wv.z + hv.w*wv.w; }
            DOT(0,a0) DOT(1,a1) DOT(2,a2) DOT(3,a3)
            DOT(4,a4) DOT(5,a5) DOT(6,a6) DOT(7,a7)
#undef DOT
        }
#pragma unroll
        for (int off = 32; off; off >>= 1) {
            a0 += __shfl_xor(a0, off, 64); a1 += __shfl_xor(a1, off, 64);
            a2 += __shfl_xor(a2, off, 64); a3 += __shfl_xor(a3, off, 64);
            a4 += __shfl_xor(a4, off, 64); a5 += __shfl_xor(a5, off, 64);
            a6 += __shfl_xor(a6, off, 64); a7 += __shfl_xor(a7, off, 64);
        }
        if (lane == 0) {
            float mx = fmaxf(fmaxf(fmaxf(a0,a1),fmaxf(a2,a3)),
                             fmaxf(fmaxf(a4,a5),fmaxf(a6,a7)));
            float e0=expf(a0-mx), e1=expf(a1-mx), e2=expf(a2-mx), e3=expf(a3-mx);
            float e4=expf(a4-mx), e5=expf(a5-mx), e6=expf(a6-mx), e7=expf(a7-mx);
            float inv = 1.f / (e0+e1+e2+e3+e4+e5+e6+e7);
            float* op = outs + row * O_DIM;
            op[0]=e0*inv; op[1]=e1*inv; op[2]=e2*inv; op[3]=e3*inv;
            op[4]=e4*inv; op[5]=e5*inv; op[6]=e6*inv; op[7]=e7*inv;
        }
    }
}

extern "C" void kernel_launch(void* const* d_in, const int* in_sizes, int n_in,
                              void* d_out, int out_size, void* d_ws, size_t ws_size,
                              hipStream_t stream) {
    const float* x     = (const float*)d_in[0];   // [128][800][9]
    const float* noise = (const float*)d_in[1];   // [128][800][1024]
    const float* Win   = (const float*)d_in[2];   // [1024][9]
    const float* Wrec  = (const float*)d_in[3];   // [1024][1024]
    const float* Wout  = (const float*)d_in[4];   // [8][1024]

    float* hiddens = (float*)d_out;                                   // 104857600 f32
    float* outs    = hiddens + (size_t)B_TOT * T_LEN * H_DIM;         // 819200 f32

    unsigned short* wrec_bf = (unsigned short*)d_ws;                  // 2 MB

    cvt_wrec<<<(H_DIM * H_DIM / 4) / 256, 256, 0, stream>>>(Wrec, wrec_bf);
    rnn_scan<<<B_TOT / NB, 1024, 0, stream>>>(x, noise, Win, wrec_bf, hiddens);
    out_head<<<(B_TOT * T_LEN) / 8, 256, 0, stream>>>(hiddens, Wout, outs);
}

// Round 2
// 22617.905 us; speedup vs baseline: 2.1720x; 2.1720x over previous
//
#include <hip/hip_runtime.h>

#define B_TOT 128
#define T_LEN 800
#define I_DIM 9
#define H_DIM 1024
#define O_DIM 8
#define NB    16            // batches per group (one M=16 MFMA tile)
#define NSLC  16            // blocks per group (N-split)
#define NCOL  64            // output columns per block
#define GROUPS (B_TOT / NB) // 8

typedef float f32x4 __attribute__((ext_vector_type(4)));
typedef short s16x8 __attribute__((ext_vector_type(8)));

__device__ __forceinline__ unsigned short f2bf(float f) {
    unsigned u = __float_as_uint(f);
    u += 0x7fffu + ((u >> 16) & 1u);   // round-to-nearest-even
    return (unsigned short)(u >> 16);
}

// -------- recurrent scan: 128 blocks (8 batch-groups x 16 N-slices) ---------
// Each block owns 64 output columns for 16 batches; its Wrec slice (128 KB
// bf16, frag-ordered) lives in LDS for all 800 steps. Hidden state is
// exchanged between the 16 blocks of a group through a double-buffered bf16
// global buffer with one device-scope counter barrier per step.
__global__ __launch_bounds__(256)
void rnn_scan(const float* __restrict__ x,        // [B][T][9]
              const float* __restrict__ noise,    // [B][T][H]
              const float* __restrict__ Win,      // [H][9]
              const float* __restrict__ Wrec,     // [H][H] f32, row n = out col
              unsigned short* __restrict__ hx,    // [G][2][NB][H] bf16 exchange
              unsigned* __restrict__ cnt,         // [G] barrier counters (stride 64)
              float* __restrict__ hiddens)        // [B][T][H] f32 out
{
    __shared__ unsigned short wf[NCOL * H_DIM];   // 128 KB, fragment-ordered
    __shared__ float xs[NB][I_DIM];

    const int tid  = threadIdx.x;
    const int lane = tid & 63;
    const int w    = tid >> 6;          // wave 0..3, owns 16 columns
    const int g    = blockIdx.x >> 4;   // batch group
    const int s    = blockIdx.x & 15;   // N-slice
    const int b0   = g * NB;
    const int l15  = lane & 15;
    const int kb   = lane >> 4;
    const int n    = s * NCOL + w * 16 + l15;   // this lane's output column

    // ---- prologue: stage Wrec slice f32 -> bf16 into frag-ordered LDS ----
    // chunk c = (wv, kt, l): holds Wrec[s*64 + wv*16 + (l&15)][kt*32 + (l>>4)*8 +: 8]
    // read back by wave wv, iter kt, lane l as a conflict-free ds_read_b128.
    for (int c = tid; c < (NCOL * H_DIM) / 8; c += 256) {
        const int wv  = c >> 11;
        const int rem = c & 2047;
        const int kt  = rem >> 6;
        const int l   = rem & 63;
        const int nn  = s * NCOL + wv * 16 + (l & 15);
        const int kk  = kt * 32 + ((l >> 4) << 3);
        const float* p = Wrec + (size_t)nn * H_DIM + kk;
        float4 v0 = *(const float4*)p;
        float4 v1 = *(const float4*)(p + 4);
        union { s16x8 v; unsigned short u[8]; } r;
        r.u[0] = f2bf(v0.x); r.u[1] = f2bf(v0.y); r.u[2] = f2bf(v0.z); r.u[3] = f2bf(v0.w);
        r.u[4] = f2bf(v1.x); r.u[5] = f2bf(v1.y); r.u[6] = f2bf(v1.z); r.u[7] = f2bf(v1.w);
        *(s16x8*)&wf[c * 8] = r.v;
    }

    float win[I_DIM];
#pragma unroll
    for (int i = 0; i < I_DIM; ++i) win[i] = Win[n * I_DIM + i];

    if (tid < NB * I_DIM) {
        int b = tid / I_DIM, i = tid - b * I_DIM;
        xs[b][i] = x[(size_t)(b0 + b) * (T_LEN * I_DIM) + i];   // t = 0
    }
    float nz[4];
#pragma unroll
    for (int r = 0; r < 4; ++r)
        nz[r] = noise[(size_t)(b0 + kb * 4 + r) * T_LEN * H_DIM + n];

    __syncthreads();

    unsigned short* hxg   = hx + (size_t)g * (2 * NB * H_DIM);
    unsigned*       mycnt = cnt + (g << 6);

    float hreg[4];
    // ---- t = 0: h starts at zero, pre = drive only ----
#pragma unroll
    for (int r = 0; r < 4; ++r) {
        const int b = kb * 4 + r;
        float d = 0.1f * nz[r];
#pragma unroll
        for (int i = 0; i < I_DIM; ++i) d += win[i] * xs[b][i];
        const float hn = 0.1f * fmaxf(d, 0.f);
        hreg[r] = hn;
        hxg[(size_t)b * H_DIM + n] = f2bf(hn);          // buf 0
    }
    __threadfence();
    __syncthreads();
    if (tid == 0)
        __hip_atomic_fetch_add(mycnt, 1u, __ATOMIC_RELEASE, __HIP_MEMORY_SCOPE_AGENT);
#pragma unroll
    for (int r = 0; r < 4; ++r)
        hiddens[(size_t)(b0 + kb * 4 + r) * T_LEN * H_DIM + n] = hreg[r];

    // ---- main loop ----
#pragma unroll 1
    for (int t = 1; t < T_LEN; ++t) {
        if (tid < NB * I_DIM) {
            int b = tid / I_DIM, i = tid - b * I_DIM;
            xs[b][i] = x[((size_t)(b0 + b) * T_LEN + t) * I_DIM + i];
        }
#pragma unroll
        for (int r = 0; r < 4; ++r)      // prefetch noise before the spin
            nz[r] = noise[((size_t)(b0 + kb * 4 + r) * T_LEN + t) * H_DIM + n];

        // group barrier: wait for all 16 blocks to publish h(t-1)
        const unsigned tgt = 16u * (unsigned)t;
        while (__hip_atomic_load(mycnt, __ATOMIC_ACQUIRE, __HIP_MEMORY_SCOPE_AGENT) < tgt) {}
        __syncthreads();   // xs visible; all waves past spin (acquire per wave)

        // GEMM: pre[b][n] += sum_k h[b][k] * Wrec[n][k]
        const unsigned short* hsrc = hxg + ((t - 1) & 1) * (NB * H_DIM);
        f32x4 acc = {0.f, 0.f, 0.f, 0.f};
        const int abase = l15 * H_DIM + kb * 8;
        const int bbase = (w * 2048 + lane) * 8;
#pragma unroll 8
        for (int kt = 0; kt < 32; ++kt) {
            s16x8 af = *(const s16x8*)&hsrc[abase + kt * 32];   // global (L3)
            s16x8 bf = *(const s16x8*)&wf[bbase + kt * 512];    // LDS, conflict-free
            acc = __builtin_amdgcn_mfma_f32_16x16x32_bf16(af, bf, acc, 0, 0, 0);
        }

        // epilogue: h_new = 0.9 h + 0.1 relu(pre + drive); publish bf16 h
        unsigned short* hdst = hxg + (t & 1) * (NB * H_DIM);
#pragma unroll
        for (int r = 0; r < 4; ++r) {
            const int b = kb * 4 + r;
            float d = 0.1f * nz[r];
#pragma unroll
            for (int i = 0; i < I_DIM; ++i) d += win[i] * xs[b][i];
            const float pre = acc[r] + d;
            const float hn  = 0.9f * hreg[r] + 0.1f * fmaxf(pre, 0.f);
            hreg[r] = hn;
            hdst[(size_t)b * H_DIM + n] = f2bf(hn);
        }
        __threadfence();       // release hx stores (agent scope)
        __syncthreads();
        if (tid == 0)
            __hip_atomic_fetch_add(mycnt, 1u, __ATOMIC_RELEASE, __HIP_MEMORY_SCOPE_AGENT);
        // hiddens store off the critical path (drains under next step's spin)
#pragma unroll
        for (int r = 0; r < 4; ++r)
            hiddens[((size_t)(b0 + kb * 4 + r) * T_LEN + t) * H_DIM + n] = hreg[r];
    }
}

// ---------------- output head: logits + softmax ----------------------------
__global__ __launch_bounds__(256)
void out_head(const float* __restrict__ hiddens, const float* __restrict__ Wout,
              float* __restrict__ outs)
{
    __shared__ float wlds[O_DIM][H_DIM];   // 32 KB
    const int tid = threadIdx.x;
    for (int j = tid; j < (O_DIM * H_DIM) / 4; j += 256)
        ((float4*)wlds)[j] = ((const float4*)Wout)[j];
    __syncthreads();

    const int wave = tid >> 6, lane = tid & 63;
#pragma unroll
    for (int rr = 0; rr < 2; ++rr) {
        const size_t row = (size_t)blockIdx.x * 8 + wave * 2 + rr;  // < 102400
        const float* hp = hiddens + row * H_DIM;

        float a0=0,a1=0,a2=0,a3=0,a4=0,a5=0,a6=0,a7=0;
#pragma unroll
        for (int j = 0; j < 4; ++j) {
            float4 hv = *(const float4*)(hp + lane * 4 + j * 256);
#define DOT(o, acc) { float4 wv = *(const float4*)&wlds[o][lane*4 + j*256]; \
                      acc += hv.x*wv.x + hv.y*wv.y + hv.z*wv.z + hv.w*wv.w; }
            DOT(0,a0) DOT(1,a1) DOT(2,a2) DOT(3,a3)
            DOT(4,a4) DOT(5,a5) DOT(6,a6) DOT(7,a7)
#undef DOT
        }
#pragma unroll
        for (int off = 32; off; off >>= 1) {
            a0 += __shfl_xor(a0, off, 64); a1 += __shfl_xor(a1, off, 64);
            a2 += __shfl_xor(a2, off, 64); a3 += __shfl_xor(a3, off, 64);
            a4 += __shfl_xor(a4, off, 64); a5 += __shfl_xor(a5, off, 64);
            a6 += __shfl_xor(a6, off, 64); a7 += __shfl_xor(a7, off, 64);
        }
        if (lane == 0) {
            float mx = fmaxf(fmaxf(fmaxf(a0,a1),fmaxf(a2,a3)),
                             fmaxf(fmaxf(a4,a5),fmaxf(a6,a7)));
            float e0=expf(a0-mx), e1=expf(a1-mx), e2=expf(a2-mx), e3=expf(a3-mx);
            float e4=expf(a4-mx), e5=expf(a5-mx), e6=expf(a6-mx), e7=expf(a7-mx);
            float inv = 1.f / (e0+e1+e2+e3+e4+e5+e6+e7);
            float* op = outs + row * O_DIM;
            op[0]=e0*inv; op[1]=e1*inv; op[2]=e2*inv; op[3]=e3*inv;
            op[4]=e4*inv; op[5]=e5*inv; op[6]=e6*inv; op[7]=e7*inv;
        }
    }
}

extern "C" void kernel_launch(void* const* d_in, const int* in_sizes, int n_in,
                              void* d_out, int out_size, void* d_ws, size_t ws_size,
                              hipStream_t stream) {
    const float* x     = (const float*)d_in[0];   // [128][800][9]
    const float* noise = (const float*)d_in[1];   // [128][800][1024]
    const float* Win   = (const float*)d_in[2];   // [1024][9]
    const float* Wrec  = (const float*)d_in[3];   // [1024][1024]
    const float* Wout  = (const float*)d_in[4];   // [8][1024]

    float* hiddens = (float*)d_out;                                // 104857600 f32
    float* outs    = hiddens + (size_t)B_TOT * T_LEN * H_DIM;      // 819200 f32

    // ws layout: [0,2KB) barrier counters (memset each launch -> deterministic
    // replay), [4KB, 4KB+512KB) bf16 h exchange double-buffer.
    unsigned*       cnt = (unsigned*)d_ws;
    unsigned short* hx  = (unsigned short*)((char*)d_ws + 4096);

    hipMemsetAsync(d_ws, 0, 4096, stream);
    rnn_scan<<<GROUPS * NSLC, 256, 0, stream>>>(x, noise, Win, Wrec, hx, cnt, hiddens);
    out_head<<<(B_TOT * T_LEN) / 8, 256, 0, stream>>>(hiddens, Wout, outs);
}

// Round 3
// 16837.939 us; speedup vs baseline: 2.9175x; 1.3433x over previous
//
#include <hip/hip_runtime.h>

#define B_TOT 128
#define T_LEN 800
#define I_DIM 9
#define H_DIM 1024
#define O_DIM 8
#define NB    16            // batches per group (one M=16 MFMA tile)
#define NSLC  16            // blocks per group (N-split)
#define NCOL  64            // output columns per block
#define GROUPS (B_TOT / NB) // 8

typedef float f32x4 __attribute__((ext_vector_type(4)));
typedef short s16x8 __attribute__((ext_vector_type(8)));

__device__ __forceinline__ unsigned short f2bf(float f) {
    unsigned u = __float_as_uint(f);
    u += 0x7fffu + ((u >> 16) & 1u);   // round-to-nearest-even
    return (unsigned short)(u >> 16);
}

// -------- recurrent scan: 128 blocks (8 batch-groups x 16 N-slices) ---------
// Each wave holds its 16 Wrec columns as bf16 MFMA B-fragments in 128 VGPRs
// (no LDS in the steady state). Per step: relaxed spin on the group counter,
// ONE acquire fence, 32x{16B L3 gather + MFMA}, epilogue, nontemporal publish,
// ONE release fence, relaxed arrive. hiddens stores drain off-path.
__global__ __launch_bounds__(256, 1)
void rnn_scan(const float* __restrict__ x,        // [B][T][9]
              const float* __restrict__ noise,    // [B][T][H]
              const float* __restrict__ Win,      // [H][9]
              const float* __restrict__ Wrec,     // [H][H] f32, row n = out col
              unsigned short* __restrict__ hx,    // [G][2][NB][H] bf16 exchange
              unsigned* __restrict__ cnt,         // [G] counters (stride 64)
              float* __restrict__ hiddens)        // [B][T][H] f32 out
{
    __shared__ float xs[NB][I_DIM];

    const int tid  = threadIdx.x;
    const int lane = tid & 63;
    const int w    = tid >> 6;          // wave 0..3, owns 16 columns
    const int g    = blockIdx.x >> 4;   // batch group
    const int s    = blockIdx.x & 15;   // N-slice
    const int b0   = g * NB;
    const int l15  = lane & 15;
    const int kb   = lane >> 4;
    const int n    = s * NCOL + w * 16 + l15;   // this lane's output column

    // ---- prologue: Wrec row n -> bf16 B-fragments in registers (128 VGPR) --
    // B[k][n] = Wrec[n][k]; lane (l15,kb) reg e of frag kt = Wrec[n][kt*32+kb*8+e]
    s16x8 breg[32];
    {
        const float* wrow = Wrec + (size_t)n * H_DIM + kb * 8;
#pragma unroll
        for (int kt = 0; kt < 32; ++kt) {
            float4 v0 = *(const float4*)(wrow + kt * 32);
            float4 v1 = *(const float4*)(wrow + kt * 32 + 4);
            union { s16x8 v; unsigned short u[8]; } r;
            r.u[0] = f2bf(v0.x); r.u[1] = f2bf(v0.y); r.u[2] = f2bf(v0.z); r.u[3] = f2bf(v0.w);
            r.u[4] = f2bf(v1.x); r.u[5] = f2bf(v1.y); r.u[6] = f2bf(v1.z); r.u[7] = f2bf(v1.w);
            breg[kt] = r.v;
        }
    }

    float win[I_DIM];
#pragma unroll
    for (int i = 0; i < I_DIM; ++i) win[i] = Win[n * I_DIM + i];

    unsigned short* hxg   = hx + (size_t)g * (2 * NB * H_DIM);
    unsigned*       mycnt = cnt + (g << 6);

    float hreg[4] = {0.f, 0.f, 0.f, 0.f};

#pragma unroll 1
    for (int t = 0; t < T_LEN; ++t) {
        // ---- pre-barrier: stage x(t) to LDS, prefetch noise(t) to regs ----
        if (tid < NB * I_DIM) {
            int b = tid / I_DIM, i = tid - b * I_DIM;
            xs[b][i] = x[((size_t)(b0 + b) * T_LEN + t) * I_DIM + i];
        }
        float nz[4];
#pragma unroll
        for (int r = 0; r < 4; ++r)
            nz[r] = noise[((size_t)(b0 + kb * 4 + r) * T_LEN + t) * H_DIM + n];

        // ---- group barrier: all 16 blocks published h(t-1) ----
        if (t > 0) {
            const unsigned tgt = 16u * (unsigned)t;
            if (tid == 0)
                while (__hip_atomic_load(mycnt, __ATOMIC_RELAXED,
                                         __HIP_MEMORY_SCOPE_AGENT) < tgt) {}
        }
        __syncthreads();   // xs visible; all waves past the spin

        // ---- GEMM: acc[r] = sum_k h(t-1)[b][k] * Wrec[n][k] ----
        f32x4 acc = {0.f, 0.f, 0.f, 0.f};
        if (t > 0) {
            __builtin_amdgcn_fence(__ATOMIC_ACQUIRE, "agent");  // inv stale L1/L2
            const unsigned short* ap =
                hxg + ((t - 1) & 1) * (NB * H_DIM) + l15 * H_DIM + kb * 8;
#pragma unroll
            for (int kt = 0; kt < 32; ++kt) {
                s16x8 af = *(const s16x8*)(ap + kt * 32);   // 16B, L3 gather
                acc = __builtin_amdgcn_mfma_f32_16x16x32_bf16(af, breg[kt], acc, 0, 0, 0);
            }
        }

        // ---- epilogue + nontemporal publish of h(t) ----
        unsigned short* hdst = hxg + (t & 1) * (NB * H_DIM);
#pragma unroll
        for (int r = 0; r < 4; ++r) {
            const int b = kb * 4 + r;
            float d = 0.1f * nz[r];
#pragma unroll
            for (int i = 0; i < I_DIM; ++i) d += win[i] * xs[b][i];
            const float pre = acc[r] + d;
            const float hn  = 0.9f * hreg[r] + 0.1f * fmaxf(pre, 0.f);
            hreg[r] = hn;
            __builtin_nontemporal_store(f2bf(hn), &hdst[(size_t)b * H_DIM + n]);
        }

        // ---- arrive: one release fence per wave, relaxed add by tid 0 ----
        __builtin_amdgcn_fence(__ATOMIC_RELEASE, "agent");  // drain + make visible
        __syncthreads();                                    // all waves released
        if (tid == 0)
            __hip_atomic_fetch_add(mycnt, 1u, __ATOMIC_RELAXED,
                                   __HIP_MEMORY_SCOPE_AGENT);

        // ---- hiddens store off the critical path (drains under next spin) --
#pragma unroll
        for (int r = 0; r < 4; ++r)
            __builtin_nontemporal_store(
                hreg[r], &hiddens[((size_t)(b0 + kb * 4 + r) * T_LEN + t) * H_DIM + n]);
    }
}

// ---------------- output head: logits + softmax ----------------------------
__global__ __launch_bounds__(256)
void out_head(const float* __restrict__ hiddens, const float* __restrict__ Wout,
              float* __restrict__ outs)
{
    __shared__ float wlds[O_DIM][H_DIM];   // 32 KB
    const int tid = threadIdx.x;
    for (int j = tid; j < (O_DIM * H_DIM) / 4; j += 256)
        ((float4*)wlds)[j] = ((const float4*)Wout)[j];
    __syncthreads();

    const int wave = tid >> 6, lane = tid & 63;
#pragma unroll
    for (int rr = 0; rr < 2; ++rr) {
        const size_t row = (size_t)blockIdx.x * 8 + wave * 2 + rr;  // < 102400
        const float* hp = hiddens + row * H_DIM;

        float a0=0,a1=0,a2=0,a3=0,a4=0,a5=0,a6=0,a7=0;
#pragma unroll
        for (int j = 0; j < 4; ++j) {
            float4 hv = *(const float4*)(hp + lane * 4 + j * 256);
#define DOT(o, acc) { float4 wv = *(const float4*)&wlds[o][lane*4 + j*256]; \
                      acc += hv.x*wv.x + hv.y*wv.y + hv.z*wv.z + hv.w*wv.w; }
            DOT(0,a0) DOT(1,a1) DOT(2,a2) DOT(3,a3)
            DOT(4,a4) DOT(5,a5) DOT(6,a6) DOT(7,a7)
#undef DOT
        }
#pragma unroll
        for (int off = 32; off; off >>= 1) {
            a0 += __shfl_xor(a0, off, 64); a1 += __shfl_xor(a1, off, 64);
            a2 += __shfl_xor(a2, off, 64); a3 += __shfl_xor(a3, off, 64);
            a4 += __shfl_xor(a4, off, 64); a5 += __shfl_xor(a5, off, 64);
            a6 += __shfl_xor(a6, off, 64); a7 += __shfl_xor(a7, off, 64);
        }
        if (lane == 0) {
            float mx = fmaxf(fmaxf(fmaxf(a0,a1),fmaxf(a2,a3)),
                             fmaxf(fmaxf(a4,a5),fmaxf(a6,a7)));
            float e0=expf(a0-mx), e1=expf(a1-mx), e2=expf(a2-mx), e3=expf(a3-mx);
            float e4=expf(a4-mx), e5=expf(a5-mx), e6=expf(a6-mx), e7=expf(a7-mx);
            float inv = 1.f / (e0+e1+e2+e3+e4+e5+e6+e7);
            float* op = outs + row * O_DIM;
            op[0]=e0*inv; op[1]=e1*inv; op[2]=e2*inv; op[3]=e3*inv;
            op[4]=e4*inv; op[5]=e5*inv; op[6]=e6*inv; op[7]=e7*inv;
        }
    }
}

extern "C" void kernel_launch(void* const* d_in, const int* in_sizes, int n_in,
                              void* d_out, int out_size, void* d_ws, size_t ws_size,
                              hipStream_t stream) {
    const float* x     = (const float*)d_in[0];   // [128][800][9]
    const float* noise = (const float*)d_in[1];   // [128][800][1024]
    const float* Win   = (const float*)d_in[2];   // [1024][9]
    const float* Wrec  = (const float*)d_in[3];   // [1024][1024]
    const float* Wout  = (const float*)d_in[4];   // [8][1024]

    float* hiddens = (float*)d_out;                                // 104857600 f32
    float* outs    = hiddens + (size_t)B_TOT * T_LEN * H_DIM;      // 819200 f32

    // ws layout: [0,4KB) barrier counters (memset each launch -> deterministic
    // replay), [4KB, 4KB+512KB) bf16 h exchange double-buffer.
    unsigned*       cnt = (unsigned*)d_ws;
    unsigned short* hx  = (unsigned short*)((char*)d_ws + 4096);

    hipMemsetAsync(d_ws, 0, 4096, stream);
    rnn_scan<<<GROUPS * NSLC, 256, 0, stream>>>(x, noise, Win, Wrec, hx, cnt, hiddens);
    out_head<<<(B_TOT * T_LEN) / 8, 256, 0, stream>>>(hiddens, Wout, outs);
}

// Round 4
// 3755.724 us; speedup vs baseline: 13.0802x; 4.4833x over previous
//
#include <hip/hip_runtime.h>

#define B_TOT 128
#define T_LEN 800
#define I_DIM 9
#define H_DIM 1024
#define O_DIM 8
#define NB    16            // batches per group (one M=16 MFMA tile)
#define NSLC  8             // blocks per group (N-split)
#define NCOL  128           // output columns per block (8 waves x 16)
#define GROUPS (B_TOT / NB) // 8

typedef float f32x4 __attribute__((ext_vector_type(4)));
typedef short s16x8 __attribute__((ext_vector_type(8)));
typedef unsigned long long u64;

__device__ __forceinline__ unsigned short f2bf(float f) {
    unsigned u = __float_as_uint(f);
    u += 0x7fffu + ((u >> 16) & 1u);   // round-to-nearest-even
    return (unsigned short)(u >> 16);
}

// -------- recurrent scan: 64 blocks (8 batch-groups x 8 N-slices) -----------
// No fences, no atomic RMW anywhere. All inter-block traffic uses relaxed
// agent-scope atomics (L2-bypass, coherent at L3): packed-u32 h publishes,
// per-slice flag stores, parallel flag polls, and a cooperative 32 KB h-tile
// gather into XOR-swizzled LDS. L2 never caches hx -> nothing can be stale.
__global__ __launch_bounds__(512, 1)
void rnn_scan(const float* __restrict__ x,        // [B][T][9]
              const float* __restrict__ noise,    // [B][T][H]
              const float* __restrict__ Win,      // [H][9]
              const float* __restrict__ Wrec,     // [H][H] f32, row n = out col
              unsigned short* __restrict__ hx,    // [G][2][NB][H] bf16 exchange
              unsigned* __restrict__ flags,       // [G][NSLC] stride-32 u32
              float* __restrict__ hiddens)        // [B][T][H] f32 out
{
    __shared__ char  hlds[NB * 2048];   // 32 KB swizzled h(t-1) tile
    __shared__ float xs[NB][I_DIM];

    const int tid  = threadIdx.x;
    const int lane = tid & 63;
    const int w    = tid >> 6;          // wave 0..7, owns 16 columns
    const int g    = blockIdx.x & 7;    // group (same-XCD affinity heuristic)
    const int s    = blockIdx.x >> 3;   // N-slice 0..7
    const int b0   = g * NB;
    const int l15  = lane & 15;
    const int kb   = lane >> 4;
    const int n    = s * NCOL + w * 16 + l15;   // this lane's output column

    // ---- prologue: Wrec row n -> bf16 B-fragments in registers (128 VGPR) --
    s16x8 breg[32];
    {
        const float* wrow = Wrec + (size_t)n * H_DIM + kb * 8;
#pragma unroll
        for (int kt = 0; kt < 32; ++kt) {
            float4 v0 = *(const float4*)(wrow + kt * 32);
            float4 v1 = *(const float4*)(wrow + kt * 32 + 4);
            union { s16x8 v; unsigned short u[8]; } r;
            r.u[0] = f2bf(v0.x); r.u[1] = f2bf(v0.y); r.u[2] = f2bf(v0.z); r.u[3] = f2bf(v0.w);
            r.u[4] = f2bf(v1.x); r.u[5] = f2bf(v1.y); r.u[6] = f2bf(v1.z); r.u[7] = f2bf(v1.w);
            breg[kt] = r.v;
        }
    }

    float win[I_DIM];
#pragma unroll
    for (int i = 0; i < I_DIM; ++i) win[i] = Win[n * I_DIM + i];

    unsigned short* hxg     = hx + (size_t)g * (2 * NB * H_DIM);
    unsigned*       myflags = flags + g * (NSLC * 32);

    // cooperative-gather geometry: wave w pulls rows {2w, 2w+1}
    const int grow = 2 * w + (lane >> 5);     // 0..15
    const int gbc  = (lane & 31) * 64;        // byte col within 2048B row

    float hreg[4] = {0.f, 0.f, 0.f, 0.f};

#pragma unroll 1
    for (int t = 0; t < T_LEN; ++t) {
        // ---- pre-barrier: stage x(t), prefetch noise(t) ----
        if (tid < NB * I_DIM) {
            int b = tid / I_DIM, i = tid - b * I_DIM;
            xs[b][i] = x[((size_t)(b0 + b) * T_LEN + t) * I_DIM + i];
        }
        float nz[4];
#pragma unroll
        for (int r = 0; r < 4; ++r)
            nz[r] = noise[((size_t)(b0 + kb * 4 + r) * T_LEN + t) * H_DIM + n];

        if (t > 0) {
            // ---- wave 0 polls the 8 slice flags in parallel (no RMW) ----
            if (w == 0) {
                const unsigned tgt = (unsigned)t;
                unsigned f;
                do {
                    f = (lane < NSLC)
                        ? __hip_atomic_load(myflags + lane * 32, __ATOMIC_RELAXED,
                                            __HIP_MEMORY_SCOPE_AGENT)
                        : tgt;
                } while (__any(f < tgt));
            }
            __syncthreads();                 // all waves see barrier passed + xs
            asm volatile("" ::: "memory");   // compiler: no hoisting above spin

            // ---- cooperative gather: 32 KB h(t-1) -> swizzled LDS ----
            const char* srcrow = (const char*)(hxg + ((t - 1) & 1) * (NB * H_DIM))
                                 + grow * 2048 + gbc;
            u64 v[8];
#pragma unroll
            for (int j = 0; j < 8; ++j)
                v[j] = __hip_atomic_load((const u64*)srcrow + j, __ATOMIC_RELAXED,
                                         __HIP_MEMORY_SCOPE_AGENT);
            char* drow = hlds + grow * 2048;
#pragma unroll
            for (int j = 0; j < 4; ++j) {
                ulonglong2 q; q.x = v[2 * j]; q.y = v[2 * j + 1];
                *(ulonglong2*)(drow + ((gbc + j * 16) ^ ((grow & 7) << 4))) = q;
            }
            __syncthreads();                 // LDS tile complete
        } else {
            __syncthreads();                 // xs visibility at t = 0
        }

        // ---- GEMM from LDS: acc[r] = sum_k h(t-1)[b][k] * Wrec[n][k] ----
        f32x4 acc = {0.f, 0.f, 0.f, 0.f};
        if (t > 0) {
#pragma unroll
            for (int kt = 0; kt < 32; ++kt) {
                s16x8 af = *(const s16x8*)(hlds + l15 * 2048 +
                                           ((kt * 64 + kb * 16) ^ ((l15 & 7) << 4)));
                acc = __builtin_amdgcn_mfma_f32_16x16x32_bf16(af, breg[kt], acc, 0, 0, 0);
            }
        }

        // ---- epilogue: h_new = 0.9 h + 0.1 relu(pre + drive) ----
#pragma unroll
        for (int r = 0; r < 4; ++r) {
            const int b = kb * 4 + r;
            float d = 0.1f * nz[r];
#pragma unroll
            for (int i = 0; i < I_DIM; ++i) d += win[i] * xs[b][i];
            const float pre = acc[r] + d;
            hreg[r] = 0.9f * hreg[r] + 0.1f * fmaxf(pre, 0.f);
        }

        // ---- publish h(t): packed col-pair u32, relaxed agent (sc-bypass) ---
        unsigned* hdst32 = (unsigned*)(hxg + (t & 1) * (NB * H_DIM));
#pragma unroll
        for (int r = 0; r < 4; ++r) {
            unsigned self  = f2bf(hreg[r]);
            unsigned other = __shfl_xor(self, 1, 64);
            if (!(l15 & 1))
                __hip_atomic_store(hdst32 + (kb * 4 + r) * (H_DIM / 2) + (n >> 1),
                                   self | (other << 16), __ATOMIC_RELAXED,
                                   __HIP_MEMORY_SCOPE_AGENT);
        }
        asm volatile("s_waitcnt vmcnt(0)" ::: "memory");  // per-wave drain to L3
        __syncthreads();                                  // all waves drained
        if (tid == 0)
            __hip_atomic_store(myflags + s * 32, (unsigned)(t + 1),
                               __ATOMIC_RELAXED, __HIP_MEMORY_SCOPE_AGENT);

        // ---- hiddens store off the critical path ----
#pragma unroll
        for (int r = 0; r < 4; ++r)
            __builtin_nontemporal_store(
                hreg[r], &hiddens[((size_t)(b0 + kb * 4 + r) * T_LEN + t) * H_DIM + n]);
    }
}

// ---------------- output head: logits + softmax ----------------------------
__global__ __launch_bounds__(256)
void out_head(const float* __restrict__ hiddens, const float* __restrict__ Wout,
              float* __restrict__ outs)
{
    __shared__ float wlds[O_DIM][H_DIM];   // 32 KB
    const int tid = threadIdx.x;
    for (int j = tid; j < (O_DIM * H_DIM) / 4; j += 256)
        ((float4*)wlds)[j] = ((const float4*)Wout)[j];
    __syncthreads();

    const int wave = tid >> 6, lane = tid & 63;
#pragma unroll
    for (int rr = 0; rr < 2; ++rr) {
        const size_t row = (size_t)blockIdx.x * 8 + wave * 2 + rr;  // < 102400
        const float* hp = hiddens + row * H_DIM;

        float a0=0,a1=0,a2=0,a3=0,a4=0,a5=0,a6=0,a7=0;
#pragma unroll
        for (int j = 0; j < 4; ++j) {
            float4 hv = *(const float4*)(hp + lane * 4 + j * 256);
#define DOT(o, acc) { float4 wv = *(const float4*)&wlds[o][lane*4 + j*256]; \
                      acc += hv.x*wv.x + hv.y*wv.y + hv.z*wv.z + hv.w*wv.w; }
            DOT(0,a0) DOT(1,a1) DOT(2,a2) DOT(3,a3)
            DOT(4,a4) DOT(5,a5) DOT(6,a6) DOT(7,a7)
#undef DOT
        }
#pragma unroll
        for (int off = 32; off; off >>= 1) {
            a0 += __shfl_xor(a0, off, 64); a1 += __shfl_xor(a1, off, 64);
            a2 += __shfl_xor(a2, off, 64); a3 += __shfl_xor(a3, off, 64);
            a4 += __shfl_xor(a4, off, 64); a5 += __shfl_xor(a5, off, 64);
            a6 += __shfl_xor(a6, off, 64); a7 += __shfl_xor(a7, off, 64);
        }
        if (lane == 0) {
            float mx = fmaxf(fmaxf(fmaxf(a0,a1),fmaxf(a2,a3)),
                             fmaxf(fmaxf(a4,a5),fmaxf(a6,a7)));
            float e0=expf(a0-mx), e1=expf(a1-mx), e2=expf(a2-mx), e3=expf(a3-mx);
            float e4=expf(a4-mx), e5=expf(a5-mx), e6=expf(a6-mx), e7=expf(a7-mx);
            float inv = 1.f / (e0+e1+e2+e3+e4+e5+e6+e7);
            float* op = outs + row * O_DIM;
            op[0]=e0*inv; op[1]=e1*inv; op[2]=e2*inv; op[3]=e3*inv;
            op[4]=e4*inv; op[5]=e5*inv; op[6]=e6*inv; op[7]=e7*inv;
        }
    }
}

extern "C" void kernel_launch(void* const* d_in, const int* in_sizes, int n_in,
                              void* d_out, int out_size, void* d_ws, size_t ws_size,
                              hipStream_t stream) {
    const float* x     = (const float*)d_in[0];   // [128][800][9]
    const float* noise = (const float*)d_in[1];   // [128][800][1024]
    const float* Win   = (const float*)d_in[2];   // [1024][9]
    const float* Wrec  = (const float*)d_in[3];   // [1024][1024]
    const float* Wout  = (const float*)d_in[4];   // [8][1024]

    float* hiddens = (float*)d_out;                                // 104857600 f32
    float* outs    = hiddens + (size_t)B_TOT * T_LEN * H_DIM;      // 819200 f32

    // ws layout: [0, 8KB) flags (memset each launch -> deterministic replay),
    // [8KB, 8KB+512KB) bf16 h exchange double-buffer.
    unsigned*       flags = (unsigned*)d_ws;
    unsigned short* hx    = (unsigned short*)((char*)d_ws + 8192);

    hipMemsetAsync(d_ws, 0, 8192, stream);
    rnn_scan<<<GROUPS * NSLC, 512, 0, stream>>>(x, noise, Win, Wrec, hx, flags, hiddens);
    out_head<<<(B_TOT * T_LEN) / 8, 256, 0, stream>>>(hiddens, Wout, outs);
}